// Round 4
// baseline (507.419 us; speedup 1.0000x reference)
//
#include <hip/hip_runtime.h>
#include <hip/hip_bf16.h>

typedef float f32x4 __attribute__((ext_vector_type(4)));
typedef short s16x8 __attribute__((ext_vector_type(8)));

#define NROWS 8192
#define MCOLS 8192
#define DIM   128
#define BI    32
#define NTILE 256   // MCOLS / 32

// ---- prep: per-row norm + scale + bf16 convert (row-major out) ----
__global__ void prep_scale_rows(const float* __restrict__ x,
                                const float* __restrict__ beta,
                                __hip_bfloat16* __restrict__ outbf) {
    int row = blockIdx.x * 4 + (threadIdx.x >> 6);
    int l = threadIdx.x & 63;
    const float* xr = x + (size_t)row * DIM;
    float x0 = xr[l], x1 = xr[l + 64];
    float ss = x0 * x0 + x1 * x1;
#pragma unroll
    for (int off = 32; off >= 1; off >>= 1) ss += __shfl_xor(ss, off);
    float s = (beta ? beta[0] : 1.0f) / sqrtf(ss);
    __hip_bfloat16* o = outbf + (size_t)row * DIM;
    o[l]      = __float2bfloat16(x0 * s);
    o[l + 64] = __float2bfloat16(x1 * s);
}

// ---- prep: transpose xj -> Vt[d][j] bf16 (raw values) ----
__global__ void prep_vt(const float* __restrict__ xj, __hip_bfloat16* __restrict__ vt) {
    __shared__ float tile[64][65];
    int j0 = blockIdx.x * 64;
    int d0 = blockIdx.y * 64;
    int t = threadIdx.x; // 256
#pragma unroll
    for (int c = 0; c < 16; ++c) {
        int idx = t + 256 * c;
        int jr = idx >> 6, dc = idx & 63;
        tile[jr][dc] = xj[(size_t)(j0 + jr) * DIM + d0 + dc];
    }
    __syncthreads();
#pragma unroll
    for (int c = 0; c < 16; ++c) {
        int idx = t + 256 * c;
        int dr = idx >> 6, jc = idx & 63;
        vt[(size_t)(d0 + dr) * MCOLS + j0 + jc] = __float2bfloat16(tile[jc][dr]);
    }
}

// ---- flash attention; no max-tracking (|score| <= beta <= 1); barrier-free
//      main loop; K/V fragments from L2; adj prefetched 2 tiles deep, issued
//      AFTER K/V so counted vmcnt keeps it in flight across iterations ----
__global__ __launch_bounds__(1024, 4) void flash4(const __hip_bfloat16* __restrict__ Qbf,
                                                  const __hip_bfloat16* __restrict__ Kbf,
                                                  const __hip_bfloat16* __restrict__ Vt,
                                                  const int* __restrict__ adj,
                                                  float* __restrict__ out) {
    __shared__ char smem[66048];
    __hip_bfloat16* Plds  = (__hip_bfloat16*)smem;   // [16 waves][16][40]
    float*          Opart = (float*)smem;            // epilogue reuse: [8][16][128]
    float*          Lpart = (float*)(smem + 65536);  // epilogue: [8][16]

    const int tid  = threadIdx.x;
    const int w    = tid >> 6;
    const int lane = tid & 63;
    const int g    = lane >> 4;
    const int ln   = lane & 15;
    const int wi   = w >> 3;   // 0..1 row group (16 rows)
    const int wj   = w & 7;    // 0..7 j slice
    const int i0   = blockIdx.x * BI;
    const int ri0  = i0 + wi * 16;

    s16x8 qf[4];
#pragma unroll
    for (int kt = 0; kt < 4; ++kt)
        qf[kt] = *(const s16x8*)(Qbf + (size_t)(ri0 + ln) * DIM + kt * 32 + g * 8);

    f32x4 zero = {0.f, 0.f, 0.f, 0.f};
    f32x4 acc[8];
#pragma unroll
    for (int dt = 0; dt < 8; ++dt) acc[dt] = zero;
    float lr[4] = {0.f, 0.f, 0.f, 0.f};

    __hip_bfloat16* pme = Plds + w * 640; // [16][40] bf16 per wave

    const int* arow = adj + (size_t)(ri0 + g * 4) * MCOLS + ln;

    // prologue: adj for tiles wj and wj+8 (2-deep pipeline)
    int amc[2][4], am1[2][4];
#pragma unroll
    for (int jt2 = 0; jt2 < 2; ++jt2)
#pragma unroll
        for (int r = 0; r < 4; ++r) {
            amc[jt2][r] = arow[(size_t)r * MCOLS + wj * 32 + jt2 * 16];
            am1[jt2][r] = arow[(size_t)r * MCOLS + (wj + 8) * 32 + jt2 * 16];
        }

    for (int t = wj; t < NTILE; t += 8) {
        const int jt = t * 32;

        // K fragments (L2): rows jt + jt2*16 + ln
        s16x8 kf[2][4];
#pragma unroll
        for (int jt2 = 0; jt2 < 2; ++jt2)
#pragma unroll
            for (int kt = 0; kt < 4; ++kt)
                kf[jt2][kt] = *(const s16x8*)(Kbf + (size_t)(jt + jt2 * 16 + ln) * DIM + kt * 32 + g * 8);

        // V fragments (L2): Vt[dt*16+ln][jt + g*8 ..]
        s16x8 vf[8];
#pragma unroll
        for (int dt = 0; dt < 8; ++dt)
            vf[dt] = *(const s16x8*)(Vt + (size_t)(dt * 16 + ln) * MCOLS + jt + g * 8);

        // adj prefetch for tile t+16: issued AFTER K/V (newest in vmcnt FIFO,
        // stays in flight for 2 iterations). Fences stop the scheduler from
        // hoisting it above the K/V loads.
        __builtin_amdgcn_sched_barrier(0);
        int am2[2][4];
        if (t + 16 < NTILE) {
            const int jtn = (t + 16) * 32;
#pragma unroll
            for (int jt2 = 0; jt2 < 2; ++jt2)
#pragma unroll
                for (int r = 0; r < 4; ++r)
                    am2[jt2][r] = arow[(size_t)r * MCOLS + jtn + jt2 * 16];
        } else {
#pragma unroll
            for (int jt2 = 0; jt2 < 2; ++jt2)
#pragma unroll
                for (int r = 0; r < 4; ++r) am2[jt2][r] = 0;
        }
        __builtin_amdgcn_sched_barrier(0);

        // S = Q K^T
        f32x4 s[2];
#pragma unroll
        for (int jt2 = 0; jt2 < 2; ++jt2) {
            s[jt2] = zero;
#pragma unroll
            for (int kt = 0; kt < 4; ++kt)
                s[jt2] = __builtin_amdgcn_mfma_f32_16x16x32_bf16(qf[kt], kf[jt2][kt], s[jt2], 0, 0, 0);
        }

        // p = adj ? exp(s) : 0
#pragma unroll
        for (int r = 0; r < 4; ++r) {
            float p0 = amc[0][r] ? __expf(s[0][r]) : 0.f;
            float p1 = amc[1][r] ? __expf(s[1][r]) : 0.f;
            lr[r] += p0 + p1;
            pme[(g * 4 + r) * 40 + ln]      = __float2bfloat16(p0);
            pme[(g * 4 + r) * 40 + 16 + ln] = __float2bfloat16(p1);
        }

        // PV (same-wave LDS RAW)
        s16x8 pf = *(const s16x8*)(pme + ln * 40 + g * 8);
#pragma unroll
        for (int dt = 0; dt < 8; ++dt)
            acc[dt] = __builtin_amdgcn_mfma_f32_16x16x32_bf16(pf, vf[dt], acc[dt], 0, 0, 0);

        // rotate mask pipeline
#pragma unroll
        for (int jt2 = 0; jt2 < 2; ++jt2)
#pragma unroll
            for (int r = 0; r < 4; ++r) { amc[jt2][r] = am1[jt2][r]; am1[jt2][r] = am2[jt2][r]; }
    }

    // row sums (within 16-lane group)
#pragma unroll
    for (int r = 0; r < 4; ++r) {
        lr[r] += __shfl_xor(lr[r], 1);
        lr[r] += __shfl_xor(lr[r], 2);
        lr[r] += __shfl_xor(lr[r], 4);
        lr[r] += __shfl_xor(lr[r], 8);
    }

    // ---- merge 8 j-slice partials (plain sums) ----
#pragma unroll
    for (int rg = 0; rg < 2; ++rg) {
        __syncthreads();
        if (wi == rg) {
#pragma unroll
            for (int dt = 0; dt < 8; ++dt)
#pragma unroll
                for (int r = 0; r < 4; ++r)
                    Opart[(wj * 16 + g * 4 + r) * 128 + dt * 16 + ln] = acc[dt][r];
            if (ln == 0) {
#pragma unroll
                for (int r = 0; r < 4; ++r) Lpart[wj * 16 + g * 4 + r] = lr[r];
            }
        }
        __syncthreads();
        const int row = tid >> 6;          // 0..15
        const int c2  = (tid & 63) * 2;    // 0..126
        float L = 0.f;
#pragma unroll
        for (int p = 0; p < 8; ++p) L += Lpart[p * 16 + row];
        float o0 = 0.f, o1 = 0.f;
#pragma unroll
        for (int p = 0; p < 8; ++p) {
            const float* op = Opart + (p * 16 + row) * 128 + c2;
            o0 += op[0];
            o1 += op[1];
        }
        float inv = 1.0f / fmaxf(L, 1e-37f);
        float2 ov = {o0 * inv, o1 * inv};
        *(float2*)(out + (size_t)(i0 + rg * 16 + row) * DIM + c2) = ov;
    }
}

extern "C" void kernel_launch(void* const* d_in, const int* in_sizes, int n_in,
                              void* d_out, int out_size, void* d_ws, size_t ws_size,
                              hipStream_t stream) {
    const float* xi   = (const float*)d_in[0];
    const float* xj   = (const float*)d_in[1];
    const int*   adj  = (const int*)d_in[2];
    const float* beta = (const float*)d_in[3];
    float* out = (float*)d_out;

    char* ws = (char*)d_ws;
    __hip_bfloat16* Qbf = (__hip_bfloat16*)ws;                                   // 2 MiB
    __hip_bfloat16* Kbf = (__hip_bfloat16*)(ws + (size_t)NROWS * DIM * 2);       // 2 MiB
    __hip_bfloat16* Vt  = (__hip_bfloat16*)(ws + 2 * (size_t)NROWS * DIM * 2);   // 2 MiB

    hipLaunchKernelGGL(prep_scale_rows, dim3(2048), dim3(256), 0, stream, xi, beta, Qbf);
    hipLaunchKernelGGL(prep_scale_rows, dim3(2048), dim3(256), 0, stream, xj, (const float*)nullptr, Kbf);
    hipLaunchKernelGGL(prep_vt, dim3(128, 2), dim3(256), 0, stream, xj, Vt);
    hipLaunchKernelGGL(flash4, dim3(NROWS / BI), dim3(1024), 0, stream, Qbf, Kbf, Vt, adj, out);
}

// Round 5
// 260.057 us; speedup vs baseline: 1.9512x; 1.9512x over previous
//
#include <hip/hip_runtime.h>
#include <hip/hip_bf16.h>

typedef float f32x4 __attribute__((ext_vector_type(4)));
typedef short s16x8 __attribute__((ext_vector_type(8)));

#define NROWS 8192
#define MCOLS 8192
#define DIM   128
#define BI    32
#define NTILE 256   // MCOLS / 32

// ---- prep: per-row norm + bf16 convert for BOTH xi (scaled by beta) and xj ----
__global__ void prep_scale_both(const float* __restrict__ xi,
                                const float* __restrict__ xj,
                                const float* __restrict__ beta,
                                __hip_bfloat16* __restrict__ Qbf,
                                __hip_bfloat16* __restrict__ Kbf) {
    int gr = blockIdx.x * 4 + (threadIdx.x >> 6);  // 0..16383, wave-uniform
    int l = threadIdx.x & 63;
    const float* src;
    __hip_bfloat16* dst;
    int row;
    if (gr < NROWS) { row = gr;          src = xi; dst = Qbf; }
    else            { row = gr - NROWS;  src = xj; dst = Kbf; }
    const float* xr = src + (size_t)row * DIM;
    float x0 = xr[l], x1 = xr[l + 64];
    float ss = x0 * x0 + x1 * x1;
#pragma unroll
    for (int off = 32; off >= 1; off >>= 1) ss += __shfl_xor(ss, off);
    float s = 1.0f / sqrtf(ss);
    if (gr < NROWS) s *= beta[0];
    __hip_bfloat16* o = dst + (size_t)row * DIM;
    o[l]      = __float2bfloat16(x0 * s);
    o[l + 64] = __float2bfloat16(x1 * s);
}

// ---- prep: transpose xj -> Vt[d][j] bf16 (raw values) ----
__global__ void prep_vt(const float* __restrict__ xj, __hip_bfloat16* __restrict__ vt) {
    __shared__ float tile[64][65];
    int j0 = blockIdx.x * 64;
    int d0 = blockIdx.y * 64;
    int t = threadIdx.x; // 256
#pragma unroll
    for (int c = 0; c < 16; ++c) {
        int idx = t + 256 * c;
        int jr = idx >> 6, dc = idx & 63;
        tile[jr][dc] = xj[(size_t)(j0 + jr) * DIM + d0 + dc];
    }
    __syncthreads();
#pragma unroll
    for (int c = 0; c < 16; ++c) {
        int idx = t + 256 * c;
        int dr = idx >> 6, jc = idx & 63;
        vt[(size_t)(d0 + dr) * MCOLS + j0 + jc] = __float2bfloat16(tile[jc][dr]);
    }
}

// ---- flash attention; no max-tracking (|score| <= beta < 1); barrier-free
//      main loop; explicit unroll-2 software pipeline:
//      issue V(t) -> K(t+4) -> QK -> softmax -> issue adj(t+8) -> PV.
//      FIFO order guarantees counted vmcnt waits; adj (HBM) consumed 2 bodies
//      after issue. 8 waves = 2 row-groups x 4 j-slices; rg pairs share K/V
//      fragments (L1 reuse). ~190 VGPR, launch_bounds(512,2): no spill. ----
__global__ __launch_bounds__(512, 2) void flash5(const __hip_bfloat16* __restrict__ Qbf,
                                                 const __hip_bfloat16* __restrict__ Kbf,
                                                 const __hip_bfloat16* __restrict__ Vt,
                                                 const int* __restrict__ adj,
                                                 float* __restrict__ out) {
    __shared__ char smem[33024];
    __hip_bfloat16* Plds  = (__hip_bfloat16*)smem;   // [8 waves][16][40] = 10 KiB
    float*          Opart = (float*)smem;            // epilogue reuse: [4][16][128] = 32 KiB
    float*          Lpart = (float*)(smem + 32768);  // epilogue: [4][16]

    const int tid  = threadIdx.x;
    const int w    = tid >> 6;
    const int lane = tid & 63;
    const int g    = lane >> 4;
    const int ln   = lane & 15;
    const int rg   = w >> 2;   // 0..1 row group (16 rows)
    const int wj   = w & 3;    // 0..3 j slice (64 tiles each)
    const int i0   = blockIdx.x * BI;
    const int ri0  = i0 + rg * 16;

    s16x8 qf[4];
#pragma unroll
    for (int kt = 0; kt < 4; ++kt)
        qf[kt] = *(const s16x8*)(Qbf + (size_t)(ri0 + ln) * DIM + kt * 32 + g * 8);

    f32x4 zero = {0.f, 0.f, 0.f, 0.f};
    f32x4 acc[8];
#pragma unroll
    for (int dt = 0; dt < 8; ++dt) acc[dt] = zero;
    float lr[4] = {0.f, 0.f, 0.f, 0.f};

    __hip_bfloat16* pme = Plds + w * 640; // [16][40] bf16 per wave
    const int* arow = adj + (size_t)(ri0 + g * 4) * MCOLS + ln;

    s16x8 kfA[2][4], kfB[2][4], vf[8];
    int amA[2][4], amB[2][4];

    // prologue: K for first tile; adj for first two tiles
    {
        const int j0 = wj * 32, j1 = (wj + 4) * 32;
#pragma unroll
        for (int jt2 = 0; jt2 < 2; ++jt2)
#pragma unroll
            for (int kt = 0; kt < 4; ++kt)
                kfA[jt2][kt] = *(const s16x8*)(Kbf + (size_t)(j0 + jt2 * 16 + ln) * DIM + kt * 32 + g * 8);
#pragma unroll
        for (int jt2 = 0; jt2 < 2; ++jt2)
#pragma unroll
            for (int r = 0; r < 4; ++r) {
                amA[jt2][r] = arow[(size_t)r * MCOLS + j0 + jt2 * 16];
                amB[jt2][r] = arow[(size_t)r * MCOLS + j1 + jt2 * 16];
            }
    }

#define TILE_BODY(T, KFC, KFN, AM) do {                                          \
    const int jt_  = (T) * 32;                                                   \
    const int tkn_ = ((T) + 4 < NTILE) ? (T) + 4 : wj;                           \
    const int jkn_ = tkn_ * 32;                                                  \
    const int tan_ = ((T) + 8 < NTILE) ? (T) + 8 : wj;                           \
    const int jan_ = tan_ * 32;                                                  \
    /* V for current tile (oldest in FIFO this body) */                          \
    _Pragma("unroll") for (int dt = 0; dt < 8; ++dt)                             \
        vf[dt] = *(const s16x8*)(Vt + (size_t)(dt * 16 + ln) * MCOLS + jt_ + g * 8); \
    /* K for next tile */                                                        \
    _Pragma("unroll") for (int jt2 = 0; jt2 < 2; ++jt2)                          \
        _Pragma("unroll") for (int kt = 0; kt < 4; ++kt)                         \
            KFN[jt2][kt] = *(const s16x8*)(Kbf + (size_t)(jkn_ + jt2 * 16 + ln) * DIM + kt * 32 + g * 8); \
    __builtin_amdgcn_sched_barrier(0);                                           \
    /* QK with current (pre-loaded) K */                                         \
    f32x4 s0 = zero, s1 = zero;                                                  \
    _Pragma("unroll") for (int kt = 0; kt < 4; ++kt) {                           \
        s0 = __builtin_amdgcn_mfma_f32_16x16x32_bf16(qf[kt], KFC[0][kt], s0, 0, 0, 0); \
        s1 = __builtin_amdgcn_mfma_f32_16x16x32_bf16(qf[kt], KFC[1][kt], s1, 0, 0, 0); } \
    /* softmax-lite: p = adj ? exp(s) : 0  (adj loaded 2 bodies ago) */          \
    _Pragma("unroll") for (int r = 0; r < 4; ++r) {                              \
        float p0 = AM[0][r] ? __expf(s0[r]) : 0.f;                               \
        float p1 = AM[1][r] ? __expf(s1[r]) : 0.f;                               \
        lr[r] += p0 + p1;                                                        \
        pme[(g * 4 + r) * 40 + ln]      = __float2bfloat16(p0);                  \
        pme[(g * 4 + r) * 40 + 16 + ln] = __float2bfloat16(p1); }                \
    __builtin_amdgcn_sched_barrier(0);                                           \
    /* adj refill for T+8 (newest in FIFO: stays in flight 2 bodies) */          \
    _Pragma("unroll") for (int jt2 = 0; jt2 < 2; ++jt2)                          \
        _Pragma("unroll") for (int r = 0; r < 4; ++r)                            \
            AM[jt2][r] = arow[(size_t)r * MCOLS + jan_ + jt2 * 16];              \
    __builtin_amdgcn_sched_barrier(0);                                           \
    /* PV: waits only V (oldest) -> K(t+4), adj(t+8) stay in flight */           \
    s16x8 pf = *(const s16x8*)(pme + ln * 40 + g * 8);                           \
    _Pragma("unroll") for (int dt = 0; dt < 8; ++dt)                             \
        acc[dt] = __builtin_amdgcn_mfma_f32_16x16x32_bf16(pf, vf[dt], acc[dt], 0, 0, 0); \
} while (0)

    for (int i = 0; i < 64; i += 2) {
        const int t0 = wj + 4 * i;
        TILE_BODY(t0, kfA, kfB, amA);
        TILE_BODY(t0 + 4, kfB, kfA, amB);
    }
#undef TILE_BODY

    // row sums (within 16-lane group)
#pragma unroll
    for (int r = 0; r < 4; ++r) {
        lr[r] += __shfl_xor(lr[r], 1);
        lr[r] += __shfl_xor(lr[r], 2);
        lr[r] += __shfl_xor(lr[r], 4);
        lr[r] += __shfl_xor(lr[r], 8);
    }

    // ---- merge 4 j-slice partials per row group (plain sums) ----
#pragma unroll
    for (int rgo = 0; rgo < 2; ++rgo) {
        __syncthreads();
        if (rg == rgo) {
#pragma unroll
            for (int dt = 0; dt < 8; ++dt)
#pragma unroll
                for (int r = 0; r < 4; ++r)
                    Opart[(wj * 16 + g * 4 + r) * 128 + dt * 16 + ln] = acc[dt][r];
            if (ln == 0) {
#pragma unroll
                for (int r = 0; r < 4; ++r) Lpart[wj * 16 + g * 4 + r] = lr[r];
            }
        }
        __syncthreads();
        const int row = tid >> 5;          // 0..15
        const int c4  = (tid & 31) * 4;    // 0..124
        float L = 0.f;
#pragma unroll
        for (int p = 0; p < 4; ++p) L += Lpart[p * 16 + row];
        float o0 = 0.f, o1 = 0.f, o2 = 0.f, o3 = 0.f;
#pragma unroll
        for (int p = 0; p < 4; ++p) {
            const float* op = Opart + (p * 16 + row) * 128 + c4;
            o0 += op[0]; o1 += op[1]; o2 += op[2]; o3 += op[3];
        }
        float inv = 1.0f / fmaxf(L, 1e-37f);
        float4 ov = {o0 * inv, o1 * inv, o2 * inv, o3 * inv};
        *(float4*)(out + (size_t)(i0 + rgo * 16 + row) * DIM + c4) = ov;
    }
}

extern "C" void kernel_launch(void* const* d_in, const int* in_sizes, int n_in,
                              void* d_out, int out_size, void* d_ws, size_t ws_size,
                              hipStream_t stream) {
    const float* xi   = (const float*)d_in[0];
    const float* xj   = (const float*)d_in[1];
    const int*   adj  = (const int*)d_in[2];
    const float* beta = (const float*)d_in[3];
    float* out = (float*)d_out;

    char* ws = (char*)d_ws;
    __hip_bfloat16* Qbf = (__hip_bfloat16*)ws;                                   // 2 MiB
    __hip_bfloat16* Kbf = (__hip_bfloat16*)(ws + (size_t)NROWS * DIM * 2);       // 2 MiB
    __hip_bfloat16* Vt  = (__hip_bfloat16*)(ws + 2 * (size_t)NROWS * DIM * 2);   // 2 MiB

    hipLaunchKernelGGL(prep_scale_both, dim3(4096), dim3(256), 0, stream, xi, xj, beta, Qbf, Kbf);
    hipLaunchKernelGGL(prep_vt, dim3(128, 2), dim3(256), 0, stream, xj, Vt);
    hipLaunchKernelGGL(flash5, dim3(NROWS / BI), dim3(512), 0, stream, Qbf, Kbf, Vt, adj, out);
}